// Round 1
// baseline (1077.174 us; speedup 1.0000x reference)
//
#include <hip/hip_runtime.h>
#include <math.h>

#define NP 100000
#define KN 16
#define DIM 64
constexpr float BN_EPS_F = 1e-5f;
constexpr double MS = (double)NP * (double)KN;   // 1,600,000 samples

// ---- workspace layout (float units) ----
constexpr size_t OFF_Q   = 0;                                 // [NP][64]
constexpr size_t OFF_K   = OFF_Q + (size_t)NP * DIM;          // [NP+1][64], row NP = 0
constexpr size_t OFF_V   = OFF_K + (size_t)(NP + 1) * DIM;    // [NP+1][64], row NP = 0
constexpr size_t OFF_S1  = OFF_V + (size_t)(NP + 1) * DIM;    // 9 doubles (point moments), pad 32
constexpr size_t OFF_PWE = OFF_S1 + 32;                       // 64 x float4 folded BN1 affine
constexpr size_t OFF_S2  = OFF_PWE + 256;                     // 128 doubles (BN2 sum/sumsq)
constexpr size_t OFF_BN2 = OFF_S2 + 256;                      // 128 floats (scale, shift)
// total = 19,200,800 floats = 76.8 MB

__global__ void k_init(float* __restrict__ ws) {
  int t = threadIdx.x;
  double* s1 = (double*)(ws + OFF_S1);
  double* s2 = (double*)(ws + OFF_S2);
  if (t < 9) s1[t] = 0.0;
  if (t < 128) s2[t] = 0.0;
  if (t < DIM) {
    ws[OFF_K + (size_t)NP * DIM + t] = 0.0f;   // k pad row
    ws[OFF_V + (size_t)NP * DIM + t] = 0.0f;   // v pad row
  }
}

// q,k,v = feats @ W^T + b.  Block = 4 points, wave per point, lane = out channel.
__global__ __launch_bounds__(256) void k_qkv(const float* __restrict__ feats,
    const float* __restrict__ qw, const float* __restrict__ qb,
    const float* __restrict__ kw, const float* __restrict__ kb,
    const float* __restrict__ vw, const float* __restrict__ vb,
    float* __restrict__ ws) {
  __shared__ float wq[4096], wk[4096], wv[4096];
  __shared__ float fl[4 * DIM];
  int tid = threadIdx.x;
  for (int e = tid; e < 4096; e += 256) {
    int c = e >> 6, i = e & 63;
    int d = (i >> 2) * 256 + c * 4 + (i & 3);   // [i4][c][i&3] -> float4 per lane
    wq[d] = qw[e]; wk[d] = kw[e]; wv[d] = vw[e];
  }
  int p = tid >> 6, c = tid & 63;
  size_t n = (size_t)blockIdx.x * 4 + p;
  fl[p * DIM + c] = feats[n * DIM + c];
  __syncthreads();
  float aq = qb[c], ak = kb[c], av = vb[c];
#pragma unroll
  for (int i4 = 0; i4 < 16; ++i4) {
    float4 fv = *(const float4*)(fl + p * DIM + i4 * 4);      // broadcast
    float4 a  = *(const float4*)(wq + i4 * 256 + c * 4);
    float4 b  = *(const float4*)(wk + i4 * 256 + c * 4);
    float4 g  = *(const float4*)(wv + i4 * 256 + c * 4);
    aq = fmaf(a.x, fv.x, aq); aq = fmaf(a.y, fv.y, aq);
    aq = fmaf(a.z, fv.z, aq); aq = fmaf(a.w, fv.w, aq);
    ak = fmaf(b.x, fv.x, ak); ak = fmaf(b.y, fv.y, ak);
    ak = fmaf(b.z, fv.z, ak); ak = fmaf(b.w, fv.w, ak);
    av = fmaf(g.x, fv.x, av); av = fmaf(g.y, fv.y, av);
    av = fmaf(g.z, fv.z, av); av = fmaf(g.w, fv.w, av);
  }
  ws[OFF_Q + n * DIM + c] = aq;
  ws[OFF_K + n * DIM + c] = ak;
  ws[OFF_V + n * DIM + c] = av;
}

// first/second moments of gathered (padded) points: 9 doubles
__global__ __launch_bounds__(256) void k_stats1(const int* __restrict__ nbr,
    const float* __restrict__ pts, float* __restrict__ ws) {
  double a[9] = {0, 0, 0, 0, 0, 0, 0, 0, 0};
  int stride = gridDim.x * blockDim.x;
  for (int e = blockIdx.x * 256 + threadIdx.x; e < NP * KN; e += stride) {
    int idx = nbr[e];
    int safe = idx < NP ? idx : 0;
    float x = pts[safe * 3 + 0], y = pts[safe * 3 + 1], z = pts[safe * 3 + 2];
    if (idx >= NP) { x = 1e6f; y = 1e6f; z = 1e6f; }
    a[0] += x; a[1] += y; a[2] += z;
    a[3] += (double)x * x; a[4] += (double)x * y; a[5] += (double)x * z;
    a[6] += (double)y * y; a[7] += (double)y * z; a[8] += (double)z * z;
  }
  __shared__ double red[256];
  double* s1 = (double*)(ws + OFF_S1);
  for (int j = 0; j < 9; ++j) {
    red[threadIdx.x] = a[j];
    __syncthreads();
    for (int s = 128; s > 0; s >>= 1) {
      if (threadIdx.x < s) red[threadIdx.x] += red[threadIdx.x + s];
      __syncthreads();
    }
    if (threadIdx.x == 0) atomicAdd(&s1[j], red[0]);
    __syncthreads();
  }
}

// fold BN1 into affine on xyz: p_feats = relu(pw_eff . xyz + pb_eff)
__global__ void k_fold1(const float* __restrict__ pw, const float* __restrict__ pb,
                        const float* __restrict__ pg, const float* __restrict__ pbeta,
                        float* __restrict__ ws) {
  int c = threadIdx.x;
  if (c >= DIM) return;
  double* s1 = (double*)(ws + OFF_S1);
  double inv = 1.0 / MS;
  double m0 = s1[0] * inv, m1 = s1[1] * inv, m2 = s1[2] * inv;
  double C00 = s1[3] * inv - m0 * m0;
  double C01 = s1[4] * inv - m0 * m1;
  double C02 = s1[5] * inv - m0 * m2;
  double C11 = s1[6] * inv - m1 * m1;
  double C12 = s1[7] * inv - m1 * m2;
  double C22 = s1[8] * inv - m2 * m2;
  double w0 = pw[c * 3], w1 = pw[c * 3 + 1], w2 = pw[c * 3 + 2];
  double mean = w0 * m0 + w1 * m1 + w2 * m2 + (double)pb[c];
  double var = w0 * w0 * C00 + w1 * w1 * C11 + w2 * w2 * C22
             + 2.0 * (w0 * w1 * C01 + w0 * w2 * C02 + w1 * w2 * C12);
  if (var < 0.0) var = 0.0;
  double a = (double)pg[c] / sqrt(var + (double)BN_EPS_F);
  float4 o;
  o.x = (float)(w0 * a); o.y = (float)(w1 * a); o.z = (float)(w2 * a);
  o.w = (float)(((double)pb[c] - mean) * a + (double)pbeta[c]);
  *(float4*)(ws + OFF_PWE + (size_t)c * 4) = o;
}

// per-channel sum / sumsq of w_lin = (k_g*q + p_feats) @ w_w^T + w_b over all N*K samples
__global__ __launch_bounds__(256) void k_stats2(const int* __restrict__ nbr,
    const float* __restrict__ pts, const float* __restrict__ ww,
    const float* __restrict__ wbias, float* __restrict__ ws) {
  __shared__ float wt[4096];
  __shared__ float hl[4][KN][DIM];
  __shared__ float sred[4][DIM];
  __shared__ float ssred[4][DIM];
  int tid = threadIdx.x;
  for (int e = tid; e < 4096; e += 256) {
    int c = e >> 6, i = e & 63;
    wt[(i >> 2) * 256 + c * 4 + (i & 3)] = ww[e];
  }
  __syncthreads();
  int wid = tid >> 6, c = tid & 63;
  const float* q  = ws + OFF_Q;
  const float* kt = ws + OFF_K;
  float4 pwe = *(const float4*)(ws + OFF_PWE + (size_t)c * 4);
  float wbc = wbias[c];
  float s = 0.f, ss = 0.f;
  for (int n = blockIdx.x * 4 + wid; n < NP; n += gridDim.x * 4) {
    float qc = q[(size_t)n * DIM + c];
#pragma unroll
    for (int k = 0; k < KN; ++k) {
      int idx = nbr[n * KN + k];
      int safe = idx < NP ? idx : 0;
      float x = pts[safe * 3 + 0], y = pts[safe * 3 + 1], z = pts[safe * 3 + 2];
      if (idx >= NP) { x = 1e6f; y = 1e6f; z = 1e6f; }
      float pf = fmaxf(fmaf(pwe.x, x, fmaf(pwe.y, y, fmaf(pwe.z, z, pwe.w))), 0.f);
      float kg = kt[(size_t)idx * DIM + c];   // pad row is zero
      hl[wid][k][c] = fmaf(kg, qc, pf);
    }
    __builtin_amdgcn_wave_barrier();
    float acc[KN];
#pragma unroll
    for (int k = 0; k < KN; ++k) acc[k] = wbc;
#pragma unroll
    for (int i4 = 0; i4 < 16; ++i4) {
      float4 w4 = *(const float4*)(wt + i4 * 256 + c * 4);
#pragma unroll
      for (int k = 0; k < KN; ++k) {
        float4 hv = *(const float4*)(&hl[wid][k][i4 * 4]);   // broadcast
        acc[k] = fmaf(w4.x, hv.x, acc[k]);
        acc[k] = fmaf(w4.y, hv.y, acc[k]);
        acc[k] = fmaf(w4.z, hv.z, acc[k]);
        acc[k] = fmaf(w4.w, hv.w, acc[k]);
      }
    }
    __builtin_amdgcn_wave_barrier();
#pragma unroll
    for (int k = 0; k < KN; ++k) { s += acc[k]; ss = fmaf(acc[k], acc[k], ss); }
  }
  __syncthreads();
  sred[wid][c] = s; ssred[wid][c] = ss;
  __syncthreads();
  if (tid < DIM) {
    double S = 0.0, SS = 0.0;
    for (int w = 0; w < 4; ++w) { S += (double)sred[w][tid]; SS += (double)ssred[w][tid]; }
    double* s2 = (double*)(ws + OFF_S2);
    atomicAdd(&s2[tid], S);
    atomicAdd(&s2[DIM + tid], SS);
  }
}

__global__ void k_fold2(const float* __restrict__ wg, const float* __restrict__ wbeta,
                        float* __restrict__ ws) {
  int c = threadIdx.x;
  if (c >= DIM) return;
  double* s2 = (double*)(ws + OFF_S2);
  double mean = s2[c] / MS;
  double var = s2[DIM + c] / MS - mean * mean;
  if (var < 0.0) var = 0.0;
  double a = (double)wg[c] / sqrt(var + (double)BN_EPS_F);
  ws[OFF_BN2 + c] = (float)a;
  ws[OFF_BN2 + DIM + c] = (float)((double)wbeta[c] - mean * a);
}

// final pass: recompute w_lin, BN2+relu, softmax over K (lane-local), weighted sum
__global__ __launch_bounds__(256) void k_final(const int* __restrict__ nbr,
    const float* __restrict__ pts, const float* __restrict__ ww,
    const float* __restrict__ wbias, const float* __restrict__ ws,
    float* __restrict__ out) {
  __shared__ float wt[4096];
  __shared__ float hl[4][KN][DIM];
  int tid = threadIdx.x;
  for (int e = tid; e < 4096; e += 256) {
    int c = e >> 6, i = e & 63;
    wt[(i >> 2) * 256 + c * 4 + (i & 3)] = ww[e];
  }
  __syncthreads();
  int wid = tid >> 6, c = tid & 63;
  int n = blockIdx.x * 4 + wid;
  const float* q   = ws + OFF_Q;
  const float* kt  = ws + OFF_K;
  const float* vt  = ws + OFF_V;
  const float* bn2 = ws + OFF_BN2;
  float4 pwe = *(const float4*)(ws + OFF_PWE + (size_t)c * 4);
  float wbc = wbias[c];
  float sc = bn2[c], sh = bn2[DIM + c];
  float qc = q[(size_t)n * DIM + c];
  int idxs[KN];
  float pf[KN];
#pragma unroll
  for (int k = 0; k < KN; ++k) {
    int idx = nbr[n * KN + k];
    idxs[k] = idx;
    int safe = idx < NP ? idx : 0;
    float x = pts[safe * 3 + 0], y = pts[safe * 3 + 1], z = pts[safe * 3 + 2];
    if (idx >= NP) { x = 1e6f; y = 1e6f; z = 1e6f; }
    pf[k] = fmaxf(fmaf(pwe.x, x, fmaf(pwe.y, y, fmaf(pwe.z, z, pwe.w))), 0.f);
    float kg = kt[(size_t)idx * DIM + c];
    hl[wid][k][c] = fmaf(kg, qc, pf[k]);
  }
  __builtin_amdgcn_wave_barrier();
  float acc[KN];
#pragma unroll
  for (int k = 0; k < KN; ++k) acc[k] = wbc;
#pragma unroll
  for (int i4 = 0; i4 < 16; ++i4) {
    float4 w4 = *(const float4*)(wt + i4 * 256 + c * 4);
#pragma unroll
    for (int k = 0; k < KN; ++k) {
      float4 hv = *(const float4*)(&hl[wid][k][i4 * 4]);
      acc[k] = fmaf(w4.x, hv.x, acc[k]);
      acc[k] = fmaf(w4.y, hv.y, acc[k]);
      acc[k] = fmaf(w4.z, hv.z, acc[k]);
      acc[k] = fmaf(w4.w, hv.w, acc[k]);
    }
  }
  // BN2 + ReLU -> logits; softmax over K is lane-local (lane = channel)
  float m = 0.f;   // logits >= 0 after relu, so max >= 0
#pragma unroll
  for (int k = 0; k < KN; ++k) {
    float lg = fmaxf(fmaf(acc[k], sc, sh), 0.f);
    acc[k] = lg;
    m = fmaxf(m, lg);
  }
  float se = 0.f;
#pragma unroll
  for (int k = 0; k < KN; ++k) { float e = __expf(acc[k] - m); acc[k] = e; se += e; }
  float rs = 1.0f / se;
  float att = 0.f;
#pragma unroll
  for (int k = 0; k < KN; ++k) {
    float vg = vt[(size_t)idxs[k] * DIM + c];   // pad row is zero
    att = fmaf(vg + pf[k], acc[k] * rs, att);
  }
  out[(size_t)n * DIM + c] = att;
}

extern "C" void kernel_launch(void* const* d_in, const int* in_sizes, int n_in,
                              void* d_out, int out_size, void* d_ws, size_t ws_size,
                              hipStream_t stream) {
  const float* pts   = (const float*)d_in[0];
  const int*   nbr   = (const int*)d_in[1];
  const float* feats = (const float*)d_in[2];
  const float* qw = (const float*)d_in[3];  const float* qb = (const float*)d_in[4];
  const float* kw = (const float*)d_in[5];  const float* kb = (const float*)d_in[6];
  const float* vw = (const float*)d_in[7];  const float* vb = (const float*)d_in[8];
  const float* pw = (const float*)d_in[9];  const float* pb = (const float*)d_in[10];
  const float* pg = (const float*)d_in[11]; const float* pbeta = (const float*)d_in[12];
  const float* www = (const float*)d_in[13]; const float* wb = (const float*)d_in[14];
  const float* wg  = (const float*)d_in[15]; const float* wbeta = (const float*)d_in[16];
  float* ws  = (float*)d_ws;
  float* out = (float*)d_out;

  hipLaunchKernelGGL(k_init,   dim3(1),     dim3(256), 0, stream, ws);
  hipLaunchKernelGGL(k_qkv,    dim3(NP/4),  dim3(256), 0, stream, feats, qw, qb, kw, kb, vw, vb, ws);
  hipLaunchKernelGGL(k_stats1, dim3(256),   dim3(256), 0, stream, nbr, pts, ws);
  hipLaunchKernelGGL(k_fold1,  dim3(1),     dim3(64),  0, stream, pw, pb, pg, pbeta, ws);
  hipLaunchKernelGGL(k_stats2, dim3(1024),  dim3(256), 0, stream, nbr, pts, www, wb, ws);
  hipLaunchKernelGGL(k_fold2,  dim3(1),     dim3(64),  0, stream, wg, wbeta, ws);
  hipLaunchKernelGGL(k_final,  dim3(NP/4),  dim3(256), 0, stream, nbr, pts, www, wb, ws, out);
}

// Round 2
// 847.098 us; speedup vs baseline: 1.2716x; 1.2716x over previous
//
#include <hip/hip_runtime.h>
#include <math.h>

#define NP 100000
#define KN 16
#define DIM 64
constexpr float BN_EPS_F = 1e-5f;
constexpr double MS = (double)NP * (double)KN;   // 1,600,000 samples

typedef __attribute__((ext_vector_type(8))) short short8;
typedef __attribute__((ext_vector_type(4))) float f32x4;

// ---- workspace layout (float units) ----
constexpr size_t OFF_Q   = 0;                                  // f32 [NP][64]
constexpr size_t OFF_K   = (size_t)NP * DIM;                   // bf16 [(NP+1)][64]
constexpr size_t OFF_V   = OFF_K + ((size_t)(NP + 1) * DIM + 1) / 2;
constexpr size_t OFF_S1  = OFF_V + ((size_t)(NP + 1) * DIM + 1) / 2;  // 10 doubles, pad 32
constexpr size_t OFF_PWE = OFF_S1 + 32;                        // 64 x float4 folded BN1 affine
constexpr size_t OFF_S2  = OFF_PWE + 256;                      // 128 doubles (BN2 sum/sumsq)
constexpr size_t OFF_BN2 = OFF_S2 + 256;                       // 128 floats (scale, shift)
constexpr size_t OFF_ZSE = OFF_BN2 + 128;                      // 64 f: exact shadow w_lin
constexpr size_t OFF_ZSB = OFF_ZSE + 64;                       // 64 f: bf16-path shadow w_lin

__device__ __forceinline__ ushort f2bf(float f) {
  union { float f; unsigned u; } v; v.f = f;
  unsigned u = v.u + 0x7fffu + ((v.u >> 16) & 1u);   // RNE
  return (ushort)(u >> 16);
}
__device__ __forceinline__ float bf2f(ushort b) {
  union { unsigned u; float f; } v; v.u = ((unsigned)b) << 16;
  return v.f;
}

// hoist w_w into 8 bf16x8 fragments (B-operand: n = lane&15 = cout, k = cin)
__device__ __forceinline__ void load_wfrags(const float* __restrict__ ww, int lane,
                                            short8 wf[4][2]) {
  int co = lane & 15, g = lane >> 4;
#pragma unroll
  for (int tn = 0; tn < 4; ++tn)
#pragma unroll
    for (int kk = 0; kk < 2; ++kk) {
      const float* p = ww + (size_t)(co + 16 * tn) * DIM + kk * 32 + g * 8;
      short8 f;
#pragma unroll
      for (int j = 0; j < 8; ++j) f[j] = (short)f2bf(p[j]);
      wf[tn][kk] = f;
    }
}

__global__ void k_init(float* __restrict__ ws) {
  int t = threadIdx.x;
  double* s1 = (double*)(ws + OFF_S1);
  double* s2 = (double*)(ws + OFF_S2);
  if (t < 10) s1[t] = 0.0;
  if (t < 128) s2[t] = 0.0;
  if (t < 32) {
    ((unsigned*)(ws + OFF_K))[(size_t)NP * 32 + t] = 0u;   // k pad row (64 bf16)
    ((unsigned*)(ws + OFF_V))[(size_t)NP * 32 + t] = 0u;   // v pad row
  }
}

// q,k,v = feats @ W^T + b.  Block = 4 points, wave per point, lane = out channel.
__global__ __launch_bounds__(256) void k_qkv(const float* __restrict__ feats,
    const float* __restrict__ qw, const float* __restrict__ qb,
    const float* __restrict__ kw, const float* __restrict__ kb,
    const float* __restrict__ vw, const float* __restrict__ vb,
    float* __restrict__ ws) {
  __shared__ float wq[4096], wk[4096], wv[4096];
  __shared__ float fl[4 * DIM];
  int tid = threadIdx.x;
  for (int e = tid; e < 4096; e += 256) {
    int c = e >> 6, i = e & 63;
    int d = (i >> 2) * 256 + c * 4 + (i & 3);
    wq[d] = qw[e]; wk[d] = kw[e]; wv[d] = vw[e];
  }
  int p = tid >> 6, c = tid & 63;
  size_t n = (size_t)blockIdx.x * 4 + p;
  fl[p * DIM + c] = feats[n * DIM + c];
  __syncthreads();
  float aq = qb[c], ak = kb[c], av = vb[c];
#pragma unroll
  for (int i4 = 0; i4 < 16; ++i4) {
    float4 fv = *(const float4*)(fl + p * DIM + i4 * 4);
    float4 a  = *(const float4*)(wq + i4 * 256 + c * 4);
    float4 b  = *(const float4*)(wk + i4 * 256 + c * 4);
    float4 g  = *(const float4*)(wv + i4 * 256 + c * 4);
    aq = fmaf(a.x, fv.x, aq); aq = fmaf(a.y, fv.y, aq);
    aq = fmaf(a.z, fv.z, aq); aq = fmaf(a.w, fv.w, aq);
    ak = fmaf(b.x, fv.x, ak); ak = fmaf(b.y, fv.y, ak);
    ak = fmaf(b.z, fv.z, ak); ak = fmaf(b.w, fv.w, ak);
    av = fmaf(g.x, fv.x, av); av = fmaf(g.y, fv.y, av);
    av = fmaf(g.z, fv.z, av); av = fmaf(g.w, fv.w, av);
  }
  ws[OFF_Q + n * DIM + c] = aq;
  ((ushort*)(ws + OFF_K))[n * DIM + c] = f2bf(ak);
  ((ushort*)(ws + OFF_V))[n * DIM + c] = f2bf(av);
}

// point moments (9 doubles) + shadow count
__global__ __launch_bounds__(256) void k_stats1(const int* __restrict__ nbr,
    const float* __restrict__ pts, float* __restrict__ ws) {
  double a[10] = {0, 0, 0, 0, 0, 0, 0, 0, 0, 0};
  int stride = gridDim.x * blockDim.x;
  for (int e = blockIdx.x * 256 + threadIdx.x; e < NP * KN; e += stride) {
    int idx = nbr[e];
    int safe = idx < NP ? idx : 0;
    float x = pts[safe * 3 + 0], y = pts[safe * 3 + 1], z = pts[safe * 3 + 2];
    if (idx >= NP) { x = 1e6f; y = 1e6f; z = 1e6f; a[9] += 1.0; }
    a[0] += x; a[1] += y; a[2] += z;
    a[3] += (double)x * x; a[4] += (double)x * y; a[5] += (double)x * z;
    a[6] += (double)y * y; a[7] += (double)y * z; a[8] += (double)z * z;
  }
  __shared__ double red[256];
  double* s1 = (double*)(ws + OFF_S1);
  for (int j = 0; j < 10; ++j) {
    red[threadIdx.x] = a[j];
    __syncthreads();
    for (int s = 128; s > 0; s >>= 1) {
      if (threadIdx.x < s) red[threadIdx.x] += red[threadIdx.x + s];
      __syncthreads();
    }
    if (threadIdx.x == 0) atomicAdd(&s1[j], red[0]);
    __syncthreads();
  }
}

// fold BN1 into affine on xyz
__global__ void k_fold1(const float* __restrict__ pw, const float* __restrict__ pb,
                        const float* __restrict__ pg, const float* __restrict__ pbeta,
                        float* __restrict__ ws) {
  int c = threadIdx.x;
  if (c >= DIM) return;
  double* s1 = (double*)(ws + OFF_S1);
  double inv = 1.0 / MS;
  double m0 = s1[0] * inv, m1 = s1[1] * inv, m2 = s1[2] * inv;
  double C00 = s1[3] * inv - m0 * m0, C01 = s1[4] * inv - m0 * m1;
  double C02 = s1[5] * inv - m0 * m2, C11 = s1[6] * inv - m1 * m1;
  double C12 = s1[7] * inv - m1 * m2, C22 = s1[8] * inv - m2 * m2;
  double w0 = pw[c * 3], w1 = pw[c * 3 + 1], w2 = pw[c * 3 + 2];
  double mean = w0 * m0 + w1 * m1 + w2 * m2 + (double)pb[c];
  double var = w0 * w0 * C00 + w1 * w1 * C11 + w2 * w2 * C22
             + 2.0 * (w0 * w1 * C01 + w0 * w2 * C02 + w1 * w2 * C12);
  if (var < 0.0) var = 0.0;
  double a = (double)pg[c] / sqrt(var + (double)BN_EPS_F);
  float4 o;
  o.x = (float)(w0 * a); o.y = (float)(w1 * a); o.z = (float)(w2 * a);
  o.w = (float)(((double)pb[c] - mean) * a + (double)pbeta[c]);
  *(float4*)(ws + OFF_PWE + (size_t)c * 4) = o;
}

// exact + bf16-path shadow w_lin (shadow h row == pf_shadow, one fixed vector)
__global__ void k_shadow(const float* __restrict__ ww, const float* __restrict__ wb,
                         float* __restrict__ ws) {
  __shared__ float pfs[64], pfb[64];
  int c = threadIdx.x;
  if (c >= DIM) return;
  float4 pwe = *(const float4*)(ws + OFF_PWE + (size_t)c * 4);
  float pf = fmaxf(fmaf(pwe.x, 1e6f, fmaf(pwe.y, 1e6f, fmaf(pwe.z, 1e6f, pwe.w))), 0.f);
  pfs[c] = pf;
  pfb[c] = bf2f(f2bf(pf));
  __syncthreads();
  double ze = (double)wb[c], zb = (double)wb[c];
  for (int i = 0; i < DIM; ++i) {
    float w = ww[c * DIM + i];
    ze += (double)pfs[i] * (double)w;
    zb += (double)pfb[i] * (double)bf2f(f2bf(w));
  }
  ws[OFF_ZSE + c] = (float)ze;
  ws[OFF_ZSB + c] = (float)zb;
}

// BN2 stats via MFMA: per-channel sum/sumsq of w_lin over all N*K samples
__global__ __launch_bounds__(256) void k_stats2(const int* __restrict__ nbr,
    const float* __restrict__ pts, const float* __restrict__ ww,
    const float* __restrict__ wbias, float* __restrict__ ws) {
  __shared__ ushort hl[4][16 * 64];
  __shared__ float sred[4][64], ssred[4][64];
  int tid = threadIdx.x, wid = tid >> 6, lane = tid & 63;
  int c = lane;
  short8 wf[4][2];
  load_wfrags(ww, lane, wf);
  float wbv[4];
#pragma unroll
  for (int tn = 0; tn < 4; ++tn) wbv[tn] = wbias[(lane & 15) + 16 * tn];
  const float* q = ws + OFF_Q;
  const ushort* kt = (const ushort*)(ws + OFF_K);
  float4 pwe = *(const float4*)(ws + OFF_PWE + (size_t)c * 4);
  ushort* hw = hl[wid];
  int row = lane & 15, g = lane >> 4;
  int aoff0 = row * 64 + ((g * 8) ^ ((row & 7) << 3));
  int aoff1 = row * 64 + ((32 + g * 8) ^ ((row & 7) << 3));
  float s[4] = {0, 0, 0, 0}, ssq[4] = {0, 0, 0, 0};
  for (int n = blockIdx.x * 4 + wid; n < NP; n += gridDim.x * 4) {
    float qc = q[(size_t)n * DIM + c];
#pragma unroll
    for (int k = 0; k < KN; ++k) {
      int idx = nbr[n * KN + k];
      float x, y, z;
      if (idx >= NP) { x = 1e6f; y = 1e6f; z = 1e6f; }
      else { x = pts[idx * 3]; y = pts[idx * 3 + 1]; z = pts[idx * 3 + 2]; }
      float pf = fmaxf(fmaf(pwe.x, x, fmaf(pwe.y, y, fmaf(pwe.z, z, pwe.w))), 0.f);
      float kg = bf2f(kt[(size_t)idx * DIM + c]);
      hw[k * 64 + (c ^ ((k & 7) << 3))] = f2bf(fmaf(kg, qc, pf));
    }
    __builtin_amdgcn_wave_barrier();
    short8 a0 = *(short8*)&hw[aoff0];
    short8 a1 = *(short8*)&hw[aoff1];
#pragma unroll
    for (int tn = 0; tn < 4; ++tn) {
      f32x4 acc = {wbv[tn], wbv[tn], wbv[tn], wbv[tn]};
      acc = __builtin_amdgcn_mfma_f32_16x16x32_bf16(a0, wf[tn][0], acc, 0, 0, 0);
      acc = __builtin_amdgcn_mfma_f32_16x16x32_bf16(a1, wf[tn][1], acc, 0, 0, 0);
#pragma unroll
      for (int r = 0; r < 4; ++r) {
        float zv = acc[r];
        s[tn] += zv; ssq[tn] = fmaf(zv, zv, ssq[tn]);
      }
    }
    __builtin_amdgcn_wave_barrier();
  }
#pragma unroll
  for (int t = 0; t < 4; ++t) {
    s[t] += __shfl_xor(s[t], 16);   s[t] += __shfl_xor(s[t], 32);
    ssq[t] += __shfl_xor(ssq[t], 16); ssq[t] += __shfl_xor(ssq[t], 32);
  }
  if (lane < 16) {
#pragma unroll
    for (int t = 0; t < 4; ++t) { sred[wid][lane + 16 * t] = s[t]; ssred[wid][lane + 16 * t] = ssq[t]; }
  }
  __syncthreads();
  if (tid < DIM) {
    double S = 0.0, SS = 0.0;
    for (int w = 0; w < 4; ++w) { S += (double)sred[w][tid]; SS += (double)ssred[w][tid]; }
    double* s2 = (double*)(ws + OFF_S2);
    atomicAdd(&s2[tid], S);
    atomicAdd(&s2[DIM + tid], SS);
  }
}

__global__ void k_fold2(const float* __restrict__ wg, const float* __restrict__ wbeta,
                        float* __restrict__ ws) {
  int c = threadIdx.x;
  if (c >= DIM) return;
  double* s2 = (double*)(ws + OFF_S2);
  double* s1 = (double*)(ws + OFF_S1);
  double nsh = s1[9];
  double zse = (double)ws[OFF_ZSE + c], zsb = (double)ws[OFF_ZSB + c];
  double S  = s2[c] + nsh * (zse - zsb);
  double SS = s2[DIM + c] + nsh * (zse * zse - zsb * zsb);
  double mean = S / MS;
  double var = SS / MS - mean * mean;
  if (var < 0.0) var = 0.0;
  double a = (double)wg[c] / sqrt(var + (double)BN_EPS_F);
  ws[OFF_BN2 + c] = (float)a;
  ws[OFF_BN2 + DIM + c] = (float)((double)wbeta[c] - mean * a);
}

// final pass: MFMA w_lin, BN2+relu, softmax over K (lane-local), weighted sum
__global__ __launch_bounds__(256) void k_final(const int* __restrict__ nbr,
    const float* __restrict__ pts, const float* __restrict__ ww,
    const float* __restrict__ wbias, const float* __restrict__ ws,
    float* __restrict__ out) {
  __shared__ ushort hl[4][16 * 64];
  __shared__ float zl[4][16 * 68];
  int tid = threadIdx.x, wid = tid >> 6, lane = tid & 63;
  int c = lane;
  short8 wf[4][2];
  load_wfrags(ww, lane, wf);
  float wbv[4];
#pragma unroll
  for (int tn = 0; tn < 4; ++tn) wbv[tn] = wbias[(lane & 15) + 16 * tn];
  const float* q = ws + OFF_Q;
  const ushort* kt = (const ushort*)(ws + OFF_K);
  const ushort* vt = (const ushort*)(ws + OFF_V);
  float4 pwe = *(const float4*)(ws + OFF_PWE + (size_t)c * 4);
  float sc = ws[OFF_BN2 + c], sh = ws[OFF_BN2 + DIM + c];
  float zsec = ws[OFF_ZSE + c];
  ushort* hw = hl[wid];
  float* zw = zl[wid];
  int row = lane & 15, g = lane >> 4;
  int aoff0 = row * 64 + ((g * 8) ^ ((row & 7) << 3));
  int aoff1 = row * 64 + ((32 + g * 8) ^ ((row & 7) << 3));
  int stride = gridDim.x * 4;
  for (int n = blockIdx.x * 4 + wid; n < NP; n += stride) {
    float qc = q[(size_t)n * DIM + c];
    int idxs[KN];
    float pf[KN];
#pragma unroll
    for (int k = 0; k < KN; ++k) {
      int idx = nbr[n * KN + k];
      idxs[k] = idx;
      float x, y, z;
      if (idx >= NP) { x = 1e6f; y = 1e6f; z = 1e6f; }
      else { x = pts[idx * 3]; y = pts[idx * 3 + 1]; z = pts[idx * 3 + 2]; }
      pf[k] = fmaxf(fmaf(pwe.x, x, fmaf(pwe.y, y, fmaf(pwe.z, z, pwe.w))), 0.f);
      float kg = bf2f(kt[(size_t)idx * DIM + c]);
      hw[k * 64 + (c ^ ((k & 7) << 3))] = f2bf(fmaf(kg, qc, pf[k]));
    }
    __builtin_amdgcn_wave_barrier();
    short8 a0 = *(short8*)&hw[aoff0];
    short8 a1 = *(short8*)&hw[aoff1];
#pragma unroll
    for (int tn = 0; tn < 4; ++tn) {
      f32x4 acc = {wbv[tn], wbv[tn], wbv[tn], wbv[tn]};
      acc = __builtin_amdgcn_mfma_f32_16x16x32_bf16(a0, wf[tn][0], acc, 0, 0, 0);
      acc = __builtin_amdgcn_mfma_f32_16x16x32_bf16(a1, wf[tn][1], acc, 0, 0, 0);
#pragma unroll
      for (int r = 0; r < 4; ++r)
        zw[(g * 4 + r) * 68 + (lane & 15) + 16 * tn] = acc[r];
    }
    __builtin_amdgcn_wave_barrier();
    float lg[KN];
    float m = 0.f;   // logits >= 0 after relu
#pragma unroll
    for (int k = 0; k < KN; ++k) {
      float lin = zw[k * 68 + c];
      if (idxs[k] >= NP) lin = zsec;          // exact shadow w_lin
      float t = fmaxf(fmaf(lin, sc, sh), 0.f);
      lg[k] = t; m = fmaxf(m, t);
    }
    float se = 0.f;
#pragma unroll
    for (int k = 0; k < KN; ++k) { float e = __expf(lg[k] - m); lg[k] = e; se += e; }
    float rs = 1.0f / se;
    float att = 0.f;
#pragma unroll
    for (int k = 0; k < KN; ++k) {
      float vg = bf2f(vt[(size_t)idxs[k] * DIM + c]);   // pad row is zero
      att = fmaf(vg + pf[k], lg[k] * rs, att);
    }
    out[(size_t)n * DIM + c] = att;
    __builtin_amdgcn_wave_barrier();
  }
}

extern "C" void kernel_launch(void* const* d_in, const int* in_sizes, int n_in,
                              void* d_out, int out_size, void* d_ws, size_t ws_size,
                              hipStream_t stream) {
  const float* pts   = (const float*)d_in[0];
  const int*   nbr   = (const int*)d_in[1];
  const float* feats = (const float*)d_in[2];
  const float* qw = (const float*)d_in[3];  const float* qb = (const float*)d_in[4];
  const float* kw = (const float*)d_in[5];  const float* kb = (const float*)d_in[6];
  const float* vw = (const float*)d_in[7];  const float* vb = (const float*)d_in[8];
  const float* pw = (const float*)d_in[9];  const float* pb = (const float*)d_in[10];
  const float* pg = (const float*)d_in[11]; const float* pbeta = (const float*)d_in[12];
  const float* www = (const float*)d_in[13]; const float* wb = (const float*)d_in[14];
  const float* wg  = (const float*)d_in[15]; const float* wbeta = (const float*)d_in[16];
  float* ws  = (float*)d_ws;
  float* out = (float*)d_out;

  hipLaunchKernelGGL(k_init,   dim3(1),     dim3(256), 0, stream, ws);
  hipLaunchKernelGGL(k_qkv,    dim3(NP/4),  dim3(256), 0, stream, feats, qw, qb, kw, kb, vw, vb, ws);
  hipLaunchKernelGGL(k_stats1, dim3(256),   dim3(256), 0, stream, nbr, pts, ws);
  hipLaunchKernelGGL(k_fold1,  dim3(1),     dim3(64),  0, stream, pw, pb, pg, pbeta, ws);
  hipLaunchKernelGGL(k_shadow, dim3(1),     dim3(64),  0, stream, www, wb, ws);
  hipLaunchKernelGGL(k_stats2, dim3(1024),  dim3(256), 0, stream, nbr, pts, www, wb, ws);
  hipLaunchKernelGGL(k_fold2,  dim3(1),     dim3(64),  0, stream, wg, wbeta, ws);
  hipLaunchKernelGGL(k_final,  dim3(3125),  dim3(256), 0, stream, nbr, pts, www, wb, ws, out);
}

// Round 3
// 486.508 us; speedup vs baseline: 2.2141x; 1.7412x over previous
//
#include <hip/hip_runtime.h>
#include <math.h>

#define NP 100000
#define KN 16
#define DIM 64
constexpr float BN_EPS_F = 1e-5f;
constexpr double MS = (double)NP * (double)KN;   // 1,600,000 samples

typedef __attribute__((ext_vector_type(8))) short short8;
typedef __attribute__((ext_vector_type(4))) float f32x4;

// ---- workspace layout (float units) ----
constexpr size_t OFF_Q    = 0;                                   // f32 [NP][64]
constexpr size_t OFF_K    = (size_t)NP * DIM;                    // bf16 [(NP+1)][64]
constexpr size_t OFF_V    = OFF_K + ((size_t)(NP + 1) * DIM) / 2;
constexpr size_t OFF_PTS4 = OFF_V + ((size_t)(NP + 1) * DIM) / 2; // f32x4 [(NP+1)]
constexpr size_t OFF_S1   = OFF_PTS4 + (size_t)(NP + 1) * 4;     // 10 doubles, pad 32
constexpr size_t OFF_PWE  = OFF_S1 + 32;                         // 64 x float4 folded BN1 affine
constexpr size_t OFF_S2   = OFF_PWE + 256;                       // 128 doubles (BN2 sum/sumsq)
constexpr size_t OFF_BN2  = OFF_S2 + 256;                        // 128 floats (scale, shift)
constexpr size_t OFF_ZSE  = OFF_BN2 + 128;                       // 64 f: exact shadow w_lin
constexpr size_t OFF_ZSB  = OFF_ZSE + 64;                        // 64 f: bf16-path shadow w_lin

__device__ __forceinline__ ushort f2bf(float f) {
  union { float f; unsigned u; } v; v.f = f;
  unsigned u = v.u + 0x7fffu + ((v.u >> 16) & 1u);   // RNE
  return (ushort)(u >> 16);
}
__device__ __forceinline__ float bf2f(ushort b) {
  union { unsigned u; float f; } v; v.u = ((unsigned)b) << 16;
  return v.f;
}

// hoist w_w into 8 bf16x8 fragments (B-operand: n = lane&15 = cout, k = cin)
__device__ __forceinline__ void load_wfrags(const float* __restrict__ ww, int lane,
                                            short8 wf[4][2]) {
  int co = lane & 15, g = lane >> 4;
#pragma unroll
  for (int tn = 0; tn < 4; ++tn)
#pragma unroll
    for (int kk = 0; kk < 2; ++kk) {
      const float* p = ww + (size_t)(co + 16 * tn) * DIM + kk * 32 + g * 8;
      short8 f;
#pragma unroll
      for (int j = 0; j < 8; ++j) f[j] = (short)f2bf(p[j]);
      wf[tn][kk] = f;
    }
}

__global__ void k_init(float* __restrict__ ws) {
  int t = threadIdx.x;
  double* s1 = (double*)(ws + OFF_S1);
  double* s2 = (double*)(ws + OFF_S2);
  if (t < 10) s1[t] = 0.0;
  if (t < 128) s2[t] = 0.0;
  if (t < 32) {
    ((unsigned*)(ws + OFF_K))[(size_t)NP * 32 + t] = 0u;   // k pad row (64 bf16)
    ((unsigned*)(ws + OFF_V))[(size_t)NP * 32 + t] = 0u;   // v pad row
  }
}

// build padded float4 point table; row NP = (1e6,1e6,1e6)
__global__ __launch_bounds__(256) void k_pts(const float* __restrict__ pts,
                                             float* __restrict__ ws) {
  int i = blockIdx.x * 256 + threadIdx.x;
  if (i > NP) return;
  float4 o;
  if (i < NP) { o.x = pts[i * 3]; o.y = pts[i * 3 + 1]; o.z = pts[i * 3 + 2]; o.w = 0.f; }
  else        { o.x = 1e6f; o.y = 1e6f; o.z = 1e6f; o.w = 0.f; }
  *(float4*)(ws + OFF_PTS4 + (size_t)i * 4) = o;
}

// q,k,v = feats @ W^T + b.  Grid-stride; wave per point, lane = out channel.
__global__ __launch_bounds__(256) void k_qkv(const float* __restrict__ feats,
    const float* __restrict__ qw, const float* __restrict__ qb,
    const float* __restrict__ kw, const float* __restrict__ kb,
    const float* __restrict__ vw, const float* __restrict__ vb,
    float* __restrict__ ws) {
  __shared__ float wq[4096], wk[4096], wv[4096];
  int tid = threadIdx.x;
  for (int e = tid; e < 4096; e += 256) {
    int cc = e >> 6, i = e & 63;
    int d = (i >> 2) * 256 + cc * 4 + (i & 3);   // [i4][c][i&3]
    wq[d] = qw[e]; wk[d] = kw[e]; wv[d] = vw[e];
  }
  __syncthreads();
  int p = tid >> 6, c = tid & 63;
  float bq = qb[c], bk = kb[c], bv = vb[c];
  const float4* f4 = (const float4*)feats;
  ushort* kt = (ushort*)(ws + OFF_K);
  ushort* vt = (ushort*)(ws + OFF_V);
  int stride = gridDim.x * 4;
  for (int n = blockIdx.x * 4 + p; n < NP; n += stride) {
    float aq = bq, ak = bk, av = bv;
#pragma unroll
    for (int i4 = 0; i4 < 16; ++i4) {
      float4 fv = f4[(size_t)n * 16 + i4];     // broadcast
      float4 a  = *(const float4*)(wq + i4 * 256 + c * 4);
      float4 b  = *(const float4*)(wk + i4 * 256 + c * 4);
      float4 g  = *(const float4*)(wv + i4 * 256 + c * 4);
      aq = fmaf(a.x, fv.x, aq); aq = fmaf(a.y, fv.y, aq);
      aq = fmaf(a.z, fv.z, aq); aq = fmaf(a.w, fv.w, aq);
      ak = fmaf(b.x, fv.x, ak); ak = fmaf(b.y, fv.y, ak);
      ak = fmaf(b.z, fv.z, ak); ak = fmaf(b.w, fv.w, ak);
      av = fmaf(g.x, fv.x, av); av = fmaf(g.y, fv.y, av);
      av = fmaf(g.z, fv.z, av); av = fmaf(g.w, fv.w, av);
    }
    ws[OFF_Q + (size_t)n * DIM + c] = aq;
    kt[(size_t)n * DIM + c] = f2bf(ak);
    vt[(size_t)n * DIM + c] = f2bf(av);
  }
}

// point moments (9 doubles) + shadow count, branchless via pts4
__global__ __launch_bounds__(256) void k_stats1(const int* __restrict__ nbr,
    float* __restrict__ ws) {
  const float4* pts4 = (const float4*)(ws + OFF_PTS4);
  double a[10] = {0, 0, 0, 0, 0, 0, 0, 0, 0, 0};
  int stride = gridDim.x * blockDim.x;
  for (int e = blockIdx.x * 256 + threadIdx.x; e < NP * KN; e += stride) {
    int idx = nbr[e];
    float4 p = pts4[idx];
    a[9] += (idx >= NP) ? 1.0 : 0.0;
    a[0] += p.x; a[1] += p.y; a[2] += p.z;
    a[3] += (double)p.x * p.x; a[4] += (double)p.x * p.y; a[5] += (double)p.x * p.z;
    a[6] += (double)p.y * p.y; a[7] += (double)p.y * p.z; a[8] += (double)p.z * p.z;
  }
  __shared__ double red[256];
  double* s1 = (double*)(ws + OFF_S1);
  for (int j = 0; j < 10; ++j) {
    red[threadIdx.x] = a[j];
    __syncthreads();
    for (int s = 128; s > 0; s >>= 1) {
      if (threadIdx.x < s) red[threadIdx.x] += red[threadIdx.x + s];
      __syncthreads();
    }
    if (threadIdx.x == 0) atomicAdd(&s1[j], red[0]);
    __syncthreads();
  }
}

// fold BN1 into affine on xyz
__global__ void k_fold1(const float* __restrict__ pw, const float* __restrict__ pb,
                        const float* __restrict__ pg, const float* __restrict__ pbeta,
                        float* __restrict__ ws) {
  int c = threadIdx.x;
  if (c >= DIM) return;
  double* s1 = (double*)(ws + OFF_S1);
  double inv = 1.0 / MS;
  double m0 = s1[0] * inv, m1 = s1[1] * inv, m2 = s1[2] * inv;
  double C00 = s1[3] * inv - m0 * m0, C01 = s1[4] * inv - m0 * m1;
  double C02 = s1[5] * inv - m0 * m2, C11 = s1[6] * inv - m1 * m1;
  double C12 = s1[7] * inv - m1 * m2, C22 = s1[8] * inv - m2 * m2;
  double w0 = pw[c * 3], w1 = pw[c * 3 + 1], w2 = pw[c * 3 + 2];
  double mean = w0 * m0 + w1 * m1 + w2 * m2 + (double)pb[c];
  double var = w0 * w0 * C00 + w1 * w1 * C11 + w2 * w2 * C22
             + 2.0 * (w0 * w1 * C01 + w0 * w2 * C02 + w1 * w2 * C12);
  if (var < 0.0) var = 0.0;
  double a = (double)pg[c] / sqrt(var + (double)BN_EPS_F);
  float4 o;
  o.x = (float)(w0 * a); o.y = (float)(w1 * a); o.z = (float)(w2 * a);
  o.w = (float)(((double)pb[c] - mean) * a + (double)pbeta[c]);
  *(float4*)(ws + OFF_PWE + (size_t)c * 4) = o;
}

// exact + bf16-path shadow w_lin (shadow h row == pf_shadow, one fixed vector)
__global__ void k_shadow(const float* __restrict__ ww, const float* __restrict__ wb,
                         float* __restrict__ ws) {
  __shared__ float pfs[64], pfb[64];
  int c = threadIdx.x;
  if (c >= DIM) return;
  float4 pwe = *(const float4*)(ws + OFF_PWE + (size_t)c * 4);
  float pf = fmaxf(fmaf(pwe.x, 1e6f, fmaf(pwe.y, 1e6f, fmaf(pwe.z, 1e6f, pwe.w))), 0.f);
  pfs[c] = pf;
  pfb[c] = bf2f(f2bf(pf));
  __syncthreads();
  double ze = (double)wb[c], zb = (double)wb[c];
  for (int i = 0; i < DIM; ++i) {
    float w = ww[c * DIM + i];
    ze += (double)pfs[i] * (double)w;
    zb += (double)pfb[i] * (double)bf2f(f2bf(w));
  }
  ws[OFF_ZSE + c] = (float)ze;
  ws[OFF_ZSB + c] = (float)zb;
}

// BN2 stats via MFMA: per-channel sum/sumsq of w_lin over all N*K samples
__global__ __launch_bounds__(256) void k_stats2(const int* __restrict__ nbr,
    const float* __restrict__ ww, const float* __restrict__ wbias,
    float* __restrict__ ws) {
  __shared__ ushort hl[4][16 * 64];
  __shared__ float sred[4][64], ssred[4][64];
  int tid = threadIdx.x, wid = tid >> 6, lane = tid & 63;
  int c = lane;
  short8 wf[4][2];
  load_wfrags(ww, lane, wf);
  float wbv[4];
#pragma unroll
  for (int tn = 0; tn < 4; ++tn) wbv[tn] = wbias[(lane & 15) + 16 * tn];
  const float* q = ws + OFF_Q;
  const ushort* kt = (const ushort*)(ws + OFF_K);
  const float4* pts4 = (const float4*)(ws + OFF_PTS4);
  float4 pwe = *(const float4*)(ws + OFF_PWE + (size_t)c * 4);
  ushort* hw = hl[wid];
  int row = lane & 15, g = lane >> 4;
  int aoff0 = row * 64 + ((g * 8) ^ ((row & 7) << 3));
  int aoff1 = row * 64 + ((32 + g * 8) ^ ((row & 7) << 3));
  float s[4] = {0, 0, 0, 0}, ssq[4] = {0, 0, 0, 0};
  int stride = gridDim.x * 4;
  for (int n = blockIdx.x * 4 + wid; n < NP; n += stride) {
    float qc = q[(size_t)n * DIM + c];
    const int4* nb4 = (const int4*)(nbr + n * KN);
    int4 b0 = nb4[0], b1 = nb4[1], b2 = nb4[2], b3 = nb4[3];
    int idx[KN] = {b0.x, b0.y, b0.z, b0.w, b1.x, b1.y, b1.z, b1.w,
                   b2.x, b2.y, b2.z, b2.w, b3.x, b3.y, b3.z, b3.w};
    ushort kv[KN];
#pragma unroll
    for (int k = 0; k < KN; ++k) kv[k] = kt[idx[k] * DIM + c];
#pragma unroll
    for (int k = 0; k < KN; ++k) {
      float4 P = pts4[idx[k]];
      float t = fmaf(pwe.x, P.x, fmaf(pwe.y, P.y, fmaf(pwe.z, P.z, pwe.w)));
      t = fmaxf(t, 0.f);
      hw[k * 64 + (c ^ ((k & 7) << 3))] = f2bf(fmaf(bf2f(kv[k]), qc, t));
    }
    __builtin_amdgcn_wave_barrier();
    short8 a0 = *(short8*)&hw[aoff0];
    short8 a1 = *(short8*)&hw[aoff1];
#pragma unroll
    for (int tn = 0; tn < 4; ++tn) {
      f32x4 acc = {wbv[tn], wbv[tn], wbv[tn], wbv[tn]};
      acc = __builtin_amdgcn_mfma_f32_16x16x32_bf16(a0, wf[tn][0], acc, 0, 0, 0);
      acc = __builtin_amdgcn_mfma_f32_16x16x32_bf16(a1, wf[tn][1], acc, 0, 0, 0);
#pragma unroll
      for (int r = 0; r < 4; ++r) {
        float zv = acc[r];
        s[tn] += zv; ssq[tn] = fmaf(zv, zv, ssq[tn]);
      }
    }
    __builtin_amdgcn_wave_barrier();
  }
#pragma unroll
  for (int t = 0; t < 4; ++t) {
    s[t] += __shfl_xor(s[t], 16);   s[t] += __shfl_xor(s[t], 32);
    ssq[t] += __shfl_xor(ssq[t], 16); ssq[t] += __shfl_xor(ssq[t], 32);
  }
  if (lane < 16) {
#pragma unroll
    for (int t = 0; t < 4; ++t) { sred[wid][lane + 16 * t] = s[t]; ssred[wid][lane + 16 * t] = ssq[t]; }
  }
  __syncthreads();
  if (tid < DIM) {
    double S = 0.0, SS = 0.0;
    for (int w = 0; w < 4; ++w) { S += (double)sred[w][tid]; SS += (double)ssred[w][tid]; }
    double* s2 = (double*)(ws + OFF_S2);
    atomicAdd(&s2[tid], S);
    atomicAdd(&s2[DIM + tid], SS);
  }
}

__global__ void k_fold2(const float* __restrict__ wg, const float* __restrict__ wbeta,
                        float* __restrict__ ws) {
  int c = threadIdx.x;
  if (c >= DIM) return;
  double* s2 = (double*)(ws + OFF_S2);
  double* s1 = (double*)(ws + OFF_S1);
  double nsh = s1[9];
  double zse = (double)ws[OFF_ZSE + c], zsb = (double)ws[OFF_ZSB + c];
  double S  = s2[c] + nsh * (zse - zsb);
  double SS = s2[DIM + c] + nsh * (zse * zse - zsb * zsb);
  double mean = S / MS;
  double var = SS / MS - mean * mean;
  if (var < 0.0) var = 0.0;
  double a = (double)wg[c] / sqrt(var + (double)BN_EPS_F);
  ws[OFF_BN2 + c] = (float)a;
  ws[OFF_BN2 + DIM + c] = (float)((double)wbeta[c] - mean * a);
}

// final pass: MFMA w_lin, BN2+relu, softmax over K (lane-local), weighted sum
__global__ __launch_bounds__(256) void k_final(const int* __restrict__ nbr,
    const float* __restrict__ ww, const float* __restrict__ wbias,
    const float* __restrict__ ws, float* __restrict__ out) {
  __shared__ ushort hl[4][16 * 64];
  __shared__ float zl[4][16 * 68];
  int tid = threadIdx.x, wid = tid >> 6, lane = tid & 63;
  int c = lane;
  short8 wf[4][2];
  load_wfrags(ww, lane, wf);
  float wbv[4];
#pragma unroll
  for (int tn = 0; tn < 4; ++tn) wbv[tn] = wbias[(lane & 15) + 16 * tn];
  const float* q = ws + OFF_Q;
  const ushort* kt = (const ushort*)(ws + OFF_K);
  const ushort* vt = (const ushort*)(ws + OFF_V);
  const float4* pts4 = (const float4*)(ws + OFF_PTS4);
  float4 pwe = *(const float4*)(ws + OFF_PWE + (size_t)c * 4);
  float sc = ws[OFF_BN2 + c], sh = ws[OFF_BN2 + DIM + c];
  float zsec = ws[OFF_ZSE + c];
  ushort* hw = hl[wid];
  float* zw = zl[wid];
  int row = lane & 15, g = lane >> 4;
  int aoff0 = row * 64 + ((g * 8) ^ ((row & 7) << 3));
  int aoff1 = row * 64 + ((32 + g * 8) ^ ((row & 7) << 3));
  int stride = gridDim.x * 4;
  for (int n = blockIdx.x * 4 + wid; n < NP; n += stride) {
    float qc = q[(size_t)n * DIM + c];
    const int4* nb4 = (const int4*)(nbr + n * KN);
    int4 b0 = nb4[0], b1 = nb4[1], b2 = nb4[2], b3 = nb4[3];
    int idx[KN] = {b0.x, b0.y, b0.z, b0.w, b1.x, b1.y, b1.z, b1.w,
                   b2.x, b2.y, b2.z, b2.w, b3.x, b3.y, b3.z, b3.w};
    ushort kv[KN], vv[KN];
#pragma unroll
    for (int k = 0; k < KN; ++k) kv[k] = kt[idx[k] * DIM + c];
#pragma unroll
    for (int k = 0; k < KN; ++k) vv[k] = vt[idx[k] * DIM + c];
    float pf[KN];
#pragma unroll
    for (int k = 0; k < KN; ++k) {
      float4 P = pts4[idx[k]];
      float t = fmaf(pwe.x, P.x, fmaf(pwe.y, P.y, fmaf(pwe.z, P.z, pwe.w)));
      pf[k] = fmaxf(t, 0.f);
      hw[k * 64 + (c ^ ((k & 7) << 3))] = f2bf(fmaf(bf2f(kv[k]), qc, pf[k]));
    }
    __builtin_amdgcn_wave_barrier();
    short8 a0 = *(short8*)&hw[aoff0];
    short8 a1 = *(short8*)&hw[aoff1];
#pragma unroll
    for (int tn = 0; tn < 4; ++tn) {
      f32x4 acc = {wbv[tn], wbv[tn], wbv[tn], wbv[tn]};
      acc = __builtin_amdgcn_mfma_f32_16x16x32_bf16(a0, wf[tn][0], acc, 0, 0, 0);
      acc = __builtin_amdgcn_mfma_f32_16x16x32_bf16(a1, wf[tn][1], acc, 0, 0, 0);
#pragma unroll
      for (int r = 0; r < 4; ++r)
        zw[(g * 4 + r) * 68 + (lane & 15) + 16 * tn] = acc[r];
    }
    __builtin_amdgcn_wave_barrier();
    float lg[KN];
    float m = 0.f;   // logits >= 0 after relu
#pragma unroll
    for (int k = 0; k < KN; ++k) {
      float lin = zw[k * 68 + c];
      if (idx[k] >= NP) lin = zsec;          // exact shadow w_lin
      float t = fmaxf(fmaf(lin, sc, sh), 0.f);
      lg[k] = t; m = fmaxf(m, t);
    }
    float se = 0.f;
#pragma unroll
    for (int k = 0; k < KN; ++k) { float e = __expf(lg[k] - m); lg[k] = e; se += e; }
    float rs = 1.0f / se;
    float att = 0.f;
#pragma unroll
    for (int k = 0; k < KN; ++k) {
      att = fmaf(bf2f(vv[k]) + pf[k], lg[k] * rs, att);
    }
    out[(size_t)n * DIM + c] = att;
    __builtin_amdgcn_wave_barrier();
  }
}

extern "C" void kernel_launch(void* const* d_in, const int* in_sizes, int n_in,
                              void* d_out, int out_size, void* d_ws, size_t ws_size,
                              hipStream_t stream) {
  const float* pts   = (const float*)d_in[0];
  const int*   nbr   = (const int*)d_in[1];
  const float* feats = (const float*)d_in[2];
  const float* qw = (const float*)d_in[3];  const float* qb = (const float*)d_in[4];
  const float* kw = (const float*)d_in[5];  const float* kb = (const float*)d_in[6];
  const float* vw = (const float*)d_in[7];  const float* vb = (const float*)d_in[8];
  const float* pw = (const float*)d_in[9];  const float* pb = (const float*)d_in[10];
  const float* pg = (const float*)d_in[11]; const float* pbeta = (const float*)d_in[12];
  const float* www = (const float*)d_in[13]; const float* wb = (const float*)d_in[14];
  const float* wg  = (const float*)d_in[15]; const float* wbeta = (const float*)d_in[16];
  float* ws  = (float*)d_ws;
  float* out = (float*)d_out;

  hipLaunchKernelGGL(k_init,   dim3(1),      dim3(256), 0, stream, ws);
  hipLaunchKernelGGL(k_pts,    dim3(392),    dim3(256), 0, stream, pts, ws);
  hipLaunchKernelGGL(k_qkv,    dim3(1024),   dim3(256), 0, stream, feats, qw, qb, kw, kb, vw, vb, ws);
  hipLaunchKernelGGL(k_stats1, dim3(512),    dim3(256), 0, stream, nbr, ws);
  hipLaunchKernelGGL(k_fold1,  dim3(1),      dim3(64),  0, stream, pw, pb, pg, pbeta, ws);
  hipLaunchKernelGGL(k_shadow, dim3(1),      dim3(64),  0, stream, www, wb, ws);
  hipLaunchKernelGGL(k_stats2, dim3(3125),   dim3(256), 0, stream, nbr, www, wb, ws);
  hipLaunchKernelGGL(k_fold2,  dim3(1),      dim3(64),  0, stream, wg, wbeta, ws);
  hipLaunchKernelGGL(k_final,  dim3(3125),   dim3(256), 0, stream, nbr, www, wb, ws, out);
}